// Round 6
// baseline (315.384 us; speedup 1.0000x reference)
//
#include <hip/hip_runtime.h>
#include <stdint.h>

typedef _Float16 half8 __attribute__((ext_vector_type(8)));
typedef float f32x16 __attribute__((ext_vector_type(16)));
typedef float f32x4  __attribute__((ext_vector_type(4)));

#define NH 49

__device__ __forceinline__ uint32_t pk2(float a, float b){
  auto p = __builtin_amdgcn_cvt_pkrtz(a, b);
  return __builtin_bit_cast(uint32_t, p);
}
__device__ __forceinline__ uint32_t relu2(uint32_t p){
  uint32_t r, z = 0u;
  asm("v_pk_max_f16 %0, %1, %2" : "=v"(r) : "v"(p), "v"(z));
  return r;
}

// acc C-layout regs -> packed fp16 pairs with ReLU (pure in-lane thanks to the
// phi(bit2<->bit3) weight pre-permutation).
template<int RH>
__device__ __forceinline__ void cvt4(const f32x16& c, uint32_t* d){
  d[0] = relu2(pk2(c[8*RH+0], c[8*RH+1]));
  d[1] = relu2(pk2(c[8*RH+2], c[8*RH+3]));
  d[2] = relu2(pk2(c[8*RH+4], c[8*RH+5]));
  d[3] = relu2(pk2(c[8*RH+6], c[8*RH+7]));
}
// full 64-feature relayout for one bt (both mt halves)
__device__ __forceinline__ void cvt16(const f32x16& a0, const f32x16& a1, uint32_t* d){
  cvt4<0>(a0, d+0); cvt4<1>(a0, d+4); cvt4<0>(a1, d+8); cvt4<1>(a1, d+12);
}

__device__ __forceinline__ half8 toh8(const uint32_t* d){
  union { uint32_t u[4]; half8 h; } v;
  v.u[0]=d[0]; v.u[1]=d[1]; v.u[2]=d[2]; v.u[3]=d[3];
  return v.h;
}

// Bias into MFMA C layout: c[4g+i] = sbase[32*mt + 8*g + 4*hi + i]
__device__ __forceinline__ f32x16 bias_c(const float* sbase, int mt, int hi){
  f32x16 c;
  const float* b = sbase + 32*mt + 4*hi;
  #pragma unroll
  for (int g=0; g<4; ++g){
    f32x4 v = *(const f32x4*)(b + 8*g);
    c[4*g+0]=v[0]; c[4*g+1]=v[1]; c[4*g+2]=v[2]; c[4*g+3]=v[3];
  }
  return c;
}

// phi: swap bits 2 and 3 of a 6-bit feature index (involution)
__device__ __forceinline__ int phi(int k){
  return (k & 51) | ((k & 4) << 1) | ((k & 8) >> 1);
}

// ---- prep: fp32 weights -> fp16 A-fragments (phi-permuted K columns) ----
__global__ void prep_weights(const float* __restrict__ w_in,
                             const float* __restrict__ w_hid,
                             const float* __restrict__ w_out,
                             half8* __restrict__ wf)
{
  int bid = blockIdx.x;
  int lane = threadIdx.x;
  int hi = lane >> 5, lo = lane & 31;
  half8 f;
  if (bid < 2){
    int mt = bid, row = 32*mt + lo;
    #pragma unroll
    for (int e=0; e<8; ++e){
      int k = 8*hi + e;
      f[e] = (k < 10) ? (_Float16)w_in[row*10 + k] : (_Float16)0.f;
    }
  } else if (bid < 394){
    int t = bid - 2;
    int l = t >> 3, kt = (t >> 1) & 3, mt = t & 1;
    int row = 32*mt + lo;
    #pragma unroll
    for (int e=0; e<8; ++e){
      int k = 16*kt + 8*hi + e;
      f[e] = (_Float16)w_hid[(l*64 + row)*64 + phi(k)];
    }
  } else {
    int kt = bid - 394;
    #pragma unroll
    for (int e=0; e<8; ++e){
      int k = 16*kt + 8*hi + e;
      f[e] = (lo < 10) ? (_Float16)w_out[lo*64 + phi(k)] : (_Float16)0.f;
    }
  }
  wf[bid*64 + lane] = f;
}

__device__ __forceinline__ f32x16 mfma16(half8 a, half8 b, f32x16 c){
  return __builtin_amdgcn_mfma_f32_32x32x16_f16(a, b, c, 0, 0, 0);
}

// 8-MFMA burst for one bt (kt0..kt3, both mt), bias as C at kt0
__device__ __forceinline__ void mfma8x(f32x16& am0, f32x16& am1,
    const half8 (&wlo)[4], const half8 (&whi)[4],
    const uint32_t* bfr, const f32x16& cb0, const f32x16& cb1)
{
  __builtin_amdgcn_s_setprio(1);
  half8 b0 = toh8(bfr+0);
  am0 = mfma16(wlo[0], b0, cb0);  am1 = mfma16(wlo[1], b0, cb1);
  half8 b1 = toh8(bfr+4);
  am0 = mfma16(wlo[2], b1, am0);  am1 = mfma16(wlo[3], b1, am1);
  half8 b2 = toh8(bfr+8);
  am0 = mfma16(whi[0], b2, am0);  am1 = mfma16(whi[1], b2, am1);
  half8 b3 = toh8(bfr+12);
  am0 = mfma16(whi[2], b3, am0);  am1 = mfma16(whi[3], b3, am1);
  __builtin_amdgcn_s_setprio(0);
}

// One hidden layer, bt-software-pipelined. wlo = kt0/kt1 frags (prefetched by
// the previous layer); kt2/kt3 frags loaded here (needed ~600cy later);
// next layer's kt0/kt1 prefetched into wnext mid-layer.
__device__ __forceinline__ void layer_body(
    const half8* frags_this, const half8* frags_next,
    half8 (&wlo)[4], half8 (&wnext)[4],
    const float* bl, int lane, int hi,
    f32x16 (&acc)[4][2], bool pref)
{
  half8 whi_[4];
  #pragma unroll
  for (int f=0; f<4; ++f) whi_[f] = frags_this[(4+f)*64 + lane];
  f32x16 cb0 = bias_c(bl, 0, hi);
  f32x16 cb1 = bias_c(bl, 1, hi);
  uint32_t bfrA[16], bfrB[16];
  cvt16(acc[0][0], acc[0][1], bfrA);
  cvt16(acc[1][0], acc[1][1], bfrB);                 // overlaps MFMA(bt0)
  mfma8x(acc[0][0], acc[0][1], wlo, whi_, bfrA, cb0, cb1);
  cvt16(acc[2][0], acc[2][1], bfrA);                 // overlaps MFMA(bt1)
  mfma8x(acc[1][0], acc[1][1], wlo, whi_, bfrB, cb0, cb1);
  if (pref){
    #pragma unroll
    for (int f=0; f<4; ++f) wnext[f] = frags_next[f*64 + lane];
  }
  cvt16(acc[3][0], acc[3][1], bfrB);                 // overlaps MFMA(bt2)
  mfma8x(acc[2][0], acc[2][1], wlo, whi_, bfrA, cb0, cb1);
  mfma8x(acc[3][0], acc[3][1], wlo, whi_, bfrB, cb0, cb1);
}

// ---- fused MLP: 1 wave owns 128 batch rows through all 51 layers ----
__global__ __launch_bounds__(256, 2) void mlp_fused(
    const float* __restrict__ x,
    const float* __restrict__ b_in,
    const float* __restrict__ b_hid,
    const float* __restrict__ b_out,
    const half8* __restrict__ wfrag,
    float* __restrict__ out)
{
  __shared__ __attribute__((aligned(16))) float sb[50*64 + 32];
  for (int i = threadIdx.x; i < 64; i += 256)     sb[i]      = b_in[i];
  for (int i = threadIdx.x; i < NH*64; i += 256)  sb[64 + i] = b_hid[i];
  if (threadIdx.x < 32) sb[3200 + threadIdx.x] = (threadIdx.x < 10) ? b_out[threadIdx.x] : 0.f;
  __syncthreads();   // only block-wide sync in the kernel

  const int lane = threadIdx.x & 63;
  const int wid  = threadIdx.x >> 6;
  const int hi   = lane >> 5;
  const int col  = lane & 31;
  const long rowbase = ((long)blockIdx.x * 4 + wid) * 128;
  const half8* whid = wfrag + 128;
  const float* sbh  = sb + 64;

  f32x16 acc[4][2];   // [bt][mt]: 128 batch rows x 64 features

  // rotating kt0/kt1 weight buffers; preload layer 0's before input compute
  half8 wA[4], wB[4];
  #pragma unroll
  for (int f=0; f<4; ++f) wA[f] = whid[f*64 + lane];

  // ---- input layer: x[*,10] (K padded to 16) ----
  {
    half8 a0 = wfrag[lane];
    half8 a1 = wfrag[64 + lane];
    f32x16 cb0 = bias_c(sb, 0, hi);
    f32x16 cb1 = bias_c(sb, 1, hi);
    #pragma unroll
    for (int bt=0; bt<4; ++bt){
      const float* xr = x + (rowbase + bt*32 + col) * 10;
      float xv[8];
      if (hi == 0){
        #pragma unroll
        for (int j=0;j<8;++j) xv[j] = xr[j];
      } else {
        xv[0]=xr[8]; xv[1]=xr[9];
        #pragma unroll
        for (int j=2;j<8;++j) xv[j]=0.f;
      }
      uint32_t d[4] = { pk2(xv[0],xv[1]), pk2(xv[2],xv[3]),
                        pk2(xv[4],xv[5]), pk2(xv[6],xv[7]) };
      half8 bx = toh8(d);
      acc[bt][0] = mfma16(a0, bx, cb0);
      acc[bt][1] = mfma16(a1, bx, cb1);
    }
  }

  // ---- 49 hidden layers, barrier-free, weights register-double-buffered ----
  #pragma unroll 1
  for (int h = 0; h < NH-1; h += 2){
    layer_body(whid + h*512,     whid + (h+1)*512, wA, wB,
               sbh + (h<<6),     lane, hi, acc, true);
    layer_body(whid + (h+1)*512, whid + (h+2)*512, wB, wA,
               sbh + ((h+1)<<6), lane, hi, acc, (h+2) < NH);
  }
  layer_body(whid + (NH-1)*512, whid, wA, wB,
             sbh + ((NH-1)<<6), lane, hi, acc, false);

  // ---- output layer: 64 -> 10 ----
  const half8* wo = wfrag + 128 + 392*64;
  f32x16 cbo = bias_c(sb + 3200, 0, hi);
  f32x16 oacc[4];
  #pragma unroll
  for (int bt=0; bt<4; ++bt){
    uint32_t bfr[16];
    cvt16(acc[bt][0], acc[bt][1], bfr);
    #pragma unroll
    for (int kt=0; kt<4; ++kt){
      half8 aw = wo[kt*64 + lane];
      half8 bb = toh8(bfr + 4*kt);
      oacc[bt] = (kt==0) ? mfma16(aw, bb, cbo) : mfma16(aw, bb, oacc[bt]);
    }
  }
  // D rows -> out features: hi==0: regs{0..3}->o0..3, regs{4,5}->o8,9 ; hi==1: regs{0..3}->o4..7
  #pragma unroll
  for (int bt=0; bt<4; ++bt){
    float* orow = out + (rowbase + bt*32 + col) * 10;
    if (hi == 0){
      *(float2*)(orow + 0) = make_float2(oacc[bt][0], oacc[bt][1]);
      *(float2*)(orow + 2) = make_float2(oacc[bt][2], oacc[bt][3]);
      *(float2*)(orow + 8) = make_float2(oacc[bt][4], oacc[bt][5]);
    } else {
      *(float2*)(orow + 4) = make_float2(oacc[bt][0], oacc[bt][1]);
      *(float2*)(orow + 6) = make_float2(oacc[bt][2], oacc[bt][3]);
    }
  }
}

extern "C" void kernel_launch(void* const* d_in, const int* in_sizes, int n_in,
                              void* d_out, int out_size, void* d_ws, size_t ws_size,
                              hipStream_t stream)
{
  const float* x     = (const float*)d_in[0];
  const float* w_in  = (const float*)d_in[1];
  const float* b_in  = (const float*)d_in[2];
  const float* w_hid = (const float*)d_in[3];
  const float* b_hid = (const float*)d_in[4];
  const float* w_out = (const float*)d_in[5];
  const float* b_out = (const float*)d_in[6];
  half8* wf = (half8*)d_ws;   // 398 KiB of A-fragments

  prep_weights<<<398, 64, 0, stream>>>(w_in, w_hid, w_out, wf);
  mlp_fused<<<2048, 256, 0, stream>>>(x, b_in, b_hid, b_out, wf, (float*)d_out);
}

// Round 7
// 313.731 us; speedup vs baseline: 1.0053x; 1.0053x over previous
//
#include <hip/hip_runtime.h>
#include <stdint.h>

typedef _Float16 half8 __attribute__((ext_vector_type(8)));
typedef float f32x16 __attribute__((ext_vector_type(16)));
typedef float f32x4  __attribute__((ext_vector_type(4)));

#define NH 49

__device__ __forceinline__ uint32_t pk2(float a, float b){
  auto p = __builtin_amdgcn_cvt_pkrtz(a, b);
  return __builtin_bit_cast(uint32_t, p);
}
__device__ __forceinline__ uint32_t relu2(uint32_t p){
  uint32_t r, z = 0u;
  asm("v_pk_max_f16 %0, %1, %2" : "=v"(r) : "v"(p), "v"(z));
  return r;
}

// acc C-layout regs -> packed fp16 pairs with ReLU (pure in-lane thanks to the
// phi(bit2<->bit3) weight pre-permutation).
template<int RH>
__device__ __forceinline__ void cvt4(const f32x16& c, uint32_t* d){
  d[0] = relu2(pk2(c[8*RH+0], c[8*RH+1]));
  d[1] = relu2(pk2(c[8*RH+2], c[8*RH+3]));
  d[2] = relu2(pk2(c[8*RH+4], c[8*RH+5]));
  d[3] = relu2(pk2(c[8*RH+6], c[8*RH+7]));
}
// full 64-feature relayout for one bt (both mt halves)
__device__ __forceinline__ void cvt16(const f32x16& a0, const f32x16& a1, uint32_t* d){
  cvt4<0>(a0, d+0); cvt4<1>(a0, d+4); cvt4<0>(a1, d+8); cvt4<1>(a1, d+12);
}

__device__ __forceinline__ half8 toh8(const uint32_t* d){
  union { uint32_t u[4]; half8 h; } v;
  v.u[0]=d[0]; v.u[1]=d[1]; v.u[2]=d[2]; v.u[3]=d[3];
  return v.h;
}

// Bias into MFMA C layout: c[4g+i] = sbase[32*mt + 8*g + 4*hi + i]
__device__ __forceinline__ f32x16 bias_c(const float* sbase, int mt, int hi){
  f32x16 c;
  const float* b = sbase + 32*mt + 4*hi;
  #pragma unroll
  for (int g=0; g<4; ++g){
    f32x4 v = *(const f32x4*)(b + 8*g);
    c[4*g+0]=v[0]; c[4*g+1]=v[1]; c[4*g+2]=v[2]; c[4*g+3]=v[3];
  }
  return c;
}

// phi: swap bits 2 and 3 of a 6-bit feature index (involution)
__device__ __forceinline__ int phi(int k){
  return (k & 51) | ((k & 4) << 1) | ((k & 8) >> 1);
}

// ---- prep: fp32 weights -> fp16 A-fragments (phi-permuted K columns) ----
__global__ void prep_weights(const float* __restrict__ w_in,
                             const float* __restrict__ w_hid,
                             const float* __restrict__ w_out,
                             half8* __restrict__ wf)
{
  int bid = blockIdx.x;
  int lane = threadIdx.x;
  int hi = lane >> 5, lo = lane & 31;
  half8 f;
  if (bid < 2){
    int mt = bid, row = 32*mt + lo;
    #pragma unroll
    for (int e=0; e<8; ++e){
      int k = 8*hi + e;
      f[e] = (k < 10) ? (_Float16)w_in[row*10 + k] : (_Float16)0.f;
    }
  } else if (bid < 394){
    int t = bid - 2;
    int l = t >> 3, kt = (t >> 1) & 3, mt = t & 1;
    int row = 32*mt + lo;
    #pragma unroll
    for (int e=0; e<8; ++e){
      int k = 16*kt + 8*hi + e;
      f[e] = (_Float16)w_hid[(l*64 + row)*64 + phi(k)];
    }
  } else {
    int kt = bid - 394;
    #pragma unroll
    for (int e=0; e<8; ++e){
      int k = 16*kt + 8*hi + e;
      f[e] = (lo < 10) ? (_Float16)w_out[lo*64 + phi(k)] : (_Float16)0.f;
    }
  }
  wf[bid*64 + lane] = f;
}

__device__ __forceinline__ f32x16 mfma16(half8 a, half8 b, f32x16 c){
  return __builtin_amdgcn_mfma_f32_32x32x16_f16(a, b, c, 0, 0, 0);
}

// ---- fused MLP: 1 wave owns 128 batch rows through all 51 layers.
// Barrier-free layer loop (waves free-run, anti-phase on the matrix pipe).
// acc is pinned to ARCH VGPRs via empty-asm "v" constraints each layer,
// eliminating the per-layer v_accvgpr_read traffic that dominated VALU time.
__global__ __launch_bounds__(256, 2) void mlp_fused(
    const float* __restrict__ x,
    const float* __restrict__ b_in,
    const float* __restrict__ b_hid,
    const float* __restrict__ b_out,
    const half8* __restrict__ wfrag,
    float* __restrict__ out)
{
  __shared__ __attribute__((aligned(16))) float sb[50*64 + 32];
  for (int i = threadIdx.x; i < 64; i += 256)     sb[i]      = b_in[i];
  for (int i = threadIdx.x; i < NH*64; i += 256)  sb[64 + i] = b_hid[i];
  if (threadIdx.x < 32) sb[3200 + threadIdx.x] = (threadIdx.x < 10) ? b_out[threadIdx.x] : 0.f;
  __syncthreads();   // only block-wide sync in the kernel

  const int lane = threadIdx.x & 63;
  const int wid  = threadIdx.x >> 6;
  const int hi   = lane >> 5;
  const int col  = lane & 31;
  const long rowbase = ((long)blockIdx.x * 4 + wid) * 128;
  const half8* whid = wfrag + 128;
  const float* sbh  = sb + 64;

  f32x16 acc[4][2];   // [bt][mt]: 128 batch rows x 64 features (VGPR-pinned)

  // ---- input layer: x[*,10] (K padded to 16) ----
  {
    half8 a0 = wfrag[lane];
    half8 a1 = wfrag[64 + lane];
    f32x16 cb0 = bias_c(sb, 0, hi);
    f32x16 cb1 = bias_c(sb, 1, hi);
    #pragma unroll
    for (int bt=0; bt<4; ++bt){
      const float* xr = x + (rowbase + bt*32 + col) * 10;
      float xv[8];
      if (hi == 0){
        #pragma unroll
        for (int j=0;j<8;++j) xv[j] = xr[j];
      } else {
        xv[0]=xr[8]; xv[1]=xr[9];
        #pragma unroll
        for (int j=2;j<8;++j) xv[j]=0.f;
      }
      uint32_t d[4] = { pk2(xv[0],xv[1]), pk2(xv[2],xv[3]),
                        pk2(xv[4],xv[5]), pk2(xv[6],xv[7]) };
      half8 bx = toh8(d);
      acc[bt][0] = mfma16(a0, bx, cb0);
      acc[bt][1] = mfma16(a1, bx, cb1);
    }
  }
  // pin accumulators to arch VGPRs
  #pragma unroll
  for (int bt=0; bt<4; ++bt)
    asm("" : "+v"(acc[bt][0]), "+v"(acc[bt][1]));

  // ---- 49 hidden layers, barrier-free ----
  #pragma unroll 1
  for (int h = 0; h < NH; ++h){
    const half8* wl = whid + h*512;
    half8 w[8];
    #pragma unroll
    for (int f=0; f<8; ++f) w[f] = wl[f*64 + lane];   // global, L1/L2 broadcast
    const float* bl = sbh + (h << 6);
    f32x16 cb0 = bias_c(bl, 0, hi);
    f32x16 cb1 = bias_c(bl, 1, hi);

    #pragma unroll
    for (int bt=0; bt<4; ++bt){
      uint32_t bfr[16];
      cvt16(acc[bt][0], acc[bt][1], bfr);
      __builtin_amdgcn_s_setprio(1);
      #pragma unroll
      for (int kt=0; kt<4; ++kt){
        half8 bb = toh8(bfr + 4*kt);
        acc[bt][0] = mfma16(w[2*kt    ], bb, kt ? acc[bt][0] : cb0);
        acc[bt][1] = mfma16(w[2*kt + 1], bb, kt ? acc[bt][1] : cb1);
      }
      __builtin_amdgcn_s_setprio(0);
    }
    // keep acc in arch VGPRs (no v_accvgpr_* round-trips)
    #pragma unroll
    for (int bt=0; bt<4; ++bt)
      asm("" : "+v"(acc[bt][0]), "+v"(acc[bt][1]));
  }

  // ---- output layer: 64 -> 10 ----
  const half8* wo = wfrag + 128 + 392*64;
  f32x16 cbo = bias_c(sb + 3200, 0, hi);
  f32x16 oacc[4];
  #pragma unroll
  for (int bt=0; bt<4; ++bt){
    uint32_t bfr[16];
    cvt16(acc[bt][0], acc[bt][1], bfr);
    #pragma unroll
    for (int kt=0; kt<4; ++kt){
      half8 aw = wo[kt*64 + lane];
      half8 bb = toh8(bfr + 4*kt);
      oacc[bt] = (kt==0) ? mfma16(aw, bb, cbo) : mfma16(aw, bb, oacc[bt]);
    }
  }
  // D rows -> out features: hi==0: regs{0..3}->o0..3, regs{4,5}->o8,9 ; hi==1: regs{0..3}->o4..7
  #pragma unroll
  for (int bt=0; bt<4; ++bt){
    float* orow = out + (rowbase + bt*32 + col) * 10;
    if (hi == 0){
      *(float2*)(orow + 0) = make_float2(oacc[bt][0], oacc[bt][1]);
      *(float2*)(orow + 2) = make_float2(oacc[bt][2], oacc[bt][3]);
      *(float2*)(orow + 8) = make_float2(oacc[bt][4], oacc[bt][5]);
    } else {
      *(float2*)(orow + 4) = make_float2(oacc[bt][0], oacc[bt][1]);
      *(float2*)(orow + 6) = make_float2(oacc[bt][2], oacc[bt][3]);
    }
  }
}

extern "C" void kernel_launch(void* const* d_in, const int* in_sizes, int n_in,
                              void* d_out, int out_size, void* d_ws, size_t ws_size,
                              hipStream_t stream)
{
  const float* x     = (const float*)d_in[0];
  const float* w_in  = (const float*)d_in[1];
  const float* b_in  = (const float*)d_in[2];
  const float* w_hid = (const float*)d_in[3];
  const float* b_hid = (const float*)d_in[4];
  const float* w_out = (const float*)d_in[5];
  const float* b_out = (const float*)d_in[6];
  half8* wf = (half8*)d_ws;   // 398 KiB of A-fragments

  prep_weights<<<398, 64, 0, stream>>>(w_in, w_hid, w_out, wf);
  mlp_fused<<<2048, 256, 0, stream>>>(x, b_in, b_hid, b_out, wf, (float*)d_out);
}